// Round 6
// baseline (149.883 us; speedup 1.0000x reference)
//
#include <hip/hip_runtime.h>
#include <hip/hip_bf16.h>

typedef __bf16 bf16x8 __attribute__((ext_vector_type(8)));
typedef float f32x4 __attribute__((ext_vector_type(4)));

#define LOG2E 1.4426950408889634f
#define LAMBDA_INIT 0.3555090675909693f
#define CEXP 0.18033688011112042f   // 0.125 * LOG2E
#define MOFF 11.541560327111708f    // 8 * LOG2E  (fixed raw max = 64)

// ws layout (bytes):
//  q    : [0, 4.19M)        bf16 [16384][128]
//  k    : [4.19M, 8.39M)    bf16 [16384][128]
//  vT   : [8.39M, 12.58M)   bf16 [4][128][4096]
//  accG : [12.58M, +16.78M) f32 [4][64][2][64][128]
//  lsumG: [+16.78M, +128K)  f32 [4][64][2][64]
//  WT   : [46.66M, 47.45M)  bf16 [3][128][1024]
#define K_OFF   ((size_t)16384 * 128)
#define VT_OFF  ((size_t)2 * 16384 * 128)
#define ACC_OFF_BYTES  ((size_t)12582912)
#define LSUM_OFF_BYTES (ACC_OFF_BYTES + (size_t)16777216)
#define WT_OFF_BYTES   ((size_t)46661632)

#define TILES_TOTAL 8320
#define NBLOCKS 768

__device__ __forceinline__ unsigned short f2bf(float f) {
    __hip_bfloat16 h = __float2bfloat16(f);
    unsigned short u;
    __builtin_memcpy(&u, &h, 2);
    return u;
}
__device__ __forceinline__ unsigned int cvt_pk_bf16(float a, float b) {
    unsigned int r;
    asm volatile("v_cvt_pk_bf16_f32 %0, %1, %2" : "=v"(r) : "v"(a), "v"(b));
    return r;
}

// ---------------- W pre-transpose: [1024][128] f32 -> [128][1024] bf16 ----------------
__global__ __launch_bounds__(256) void prep_wt(
    const float* __restrict__ Wq, const float* __restrict__ Wk,
    const float* __restrict__ Wv, unsigned short* __restrict__ WT) {
    const int kt = blockIdx.x, nt = blockIdx.y, mat = blockIdx.z;
    const float* W = (mat == 0) ? Wq : (mat == 1) ? Wk : Wv;
    unsigned short* O = WT + (size_t)mat * 128 * 1024;
    __shared__ float tb[64][65];
    const int r = threadIdx.x >> 2, c4 = (threadIdx.x & 3) * 16;
    for (int j = 0; j < 4; ++j) {
        float4 v = *(const float4*)&W[(size_t)(kt * 64 + r) * 128 + nt * 64 + c4 + j * 4];
        tb[r][c4 + j * 4 + 0] = v.x;
        tb[r][c4 + j * 4 + 1] = v.y;
        tb[r][c4 + j * 4 + 2] = v.z;
        tb[r][c4 + j * 4 + 3] = v.w;
    }
    __syncthreads();
    unsigned short tmp[16];
    for (int j = 0; j < 16; ++j) tmp[j] = f2bf(tb[c4 + j][r]);
    *(uint4*)&O[(size_t)(nt * 64 + r) * 1024 + kt * 64 + c4] = *(uint4*)&tmp[0];
    *(uint4*)&O[(size_t)(nt * 64 + r) * 1024 + kt * 64 + c4 + 8] = *(uint4*)&tmp[8];
}

// ---------------- QKV projection ----------------
__global__ __launch_bounds__(256) void qkv_gemm(
    const float* __restrict__ x, const unsigned short* __restrict__ WT,
    unsigned short* __restrict__ qkv) {
    const int tid = threadIdx.x;
    const int l = tid & 63, wid = tid >> 6;
    const int g = l >> 4, i16 = l & 15;
    const int row0 = blockIdx.x * 128;
    const int mat = blockIdx.y;
    const unsigned short* Wt = WT + (size_t)mat * 128 * 1024;

    __shared__ unsigned short smem[2][128][72];
    auto xs = smem[0];
    auto wt = smem[1];

    f32x4 acc[2][8];
    const f32x4 z4 = {0.f, 0.f, 0.f, 0.f};
    for (int a = 0; a < 2; ++a)
        for (int b = 0; b < 8; ++b) acc[a][b] = z4;

    for (int k0 = 0; k0 < 1024; k0 += 64) {
        __syncthreads();
        {
            const int c = (tid & 15) * 4;
            const int rbase = tid >> 4;
            #pragma unroll
            for (int it = 0; it < 8; ++it) {
                int r = rbase + it * 16;
                const float4 v = *(const float4*)&x[(size_t)(row0 + r) * 1024 + k0 + c];
                ushort4 pk = make_ushort4(f2bf(v.x), f2bf(v.y), f2bf(v.z), f2bf(v.w));
                *(ushort4*)&xs[r][c] = pk;
            }
        }
        {
            #pragma unroll
            for (int it = 0; it < 4; ++it) {
                int lin = it * 256 + tid;
                int n = lin >> 3, k8 = (lin & 7) * 8;
                *(uint4*)&wt[n][k8] = *(const uint4*)&Wt[(size_t)n * 1024 + k0 + k8];
            }
        }
        __syncthreads();

        bf16x8 af[2][2];
        for (int rb = 0; rb < 2; ++rb)
            for (int c = 0; c < 2; ++c)
                af[rb][c] = *(const bf16x8*)&xs[wid * 32 + rb * 16 + i16][c * 32 + 8 * g];
        for (int nb = 0; nb < 8; ++nb) {
            bf16x8 b0 = *(const bf16x8*)&wt[nb * 16 + i16][8 * g];
            bf16x8 b1 = *(const bf16x8*)&wt[nb * 16 + i16][32 + 8 * g];
            for (int rb = 0; rb < 2; ++rb) {
                acc[rb][nb] = __builtin_amdgcn_mfma_f32_16x16x32_bf16(af[rb][0], b0, acc[rb][nb], 0, 0, 0);
                acc[rb][nb] = __builtin_amdgcn_mfma_f32_16x16x32_bf16(af[rb][1], b1, acc[rb][nb], 0, 0, 0);
            }
        }
    }

    __syncthreads();
    unsigned short(*ts)[136] = (unsigned short(*)[136]) & smem[0][0][0];
    for (int rb = 0; rb < 2; ++rb)
        for (int nb = 0; nb < 8; ++nb)
            for (int r = 0; r < 4; ++r)
                ts[wid * 32 + rb * 16 + g * 4 + r][nb * 16 + i16] = f2bf(acc[rb][nb][r]);
    __syncthreads();
    if (mat < 2) {
        unsigned short* outp = qkv + (size_t)mat * 16384 * 128 + (size_t)row0 * 128;
        #pragma unroll
        for (int it = 0; it < 8; ++it) {
            int tr = it * 16 + (tid >> 4), dv0 = (tid & 15) * 8;
            *(uint4*)&outp[tr * 128 + dv0] = *(const uint4*)&ts[tr][dv0];
        }
    } else {
        unsigned short* vtb = qkv + VT_OFF + (size_t)(row0 >> 12) * 128 * 4096 + (size_t)(row0 & 4095);
        const int dv = tid >> 1, half = tid & 1;
        #pragma unroll
        for (int blk = 0; blk < 8; ++blk) {
            unsigned short tmp[8];
            #pragma unroll
            for (int j = 0; j < 8; ++j) tmp[j] = ts[half * 64 + blk * 8 + j][dv];
            *(uint4*)&vtb[(size_t)dv * 4096 + half * 64 + blk * 8] = *(uint4*)tmp;
        }
    }
}

// ---------------- Differential causal flash attention, persistent uniform blocks ----------
// 768 blocks, each owns a contiguous range of global tile index g in [0,8320).
// g -> (b,t,s): b = g/2080, r = g%2080, t = tri-invert(r), s = r - t(t+1)/2.
// Fixed softmax max -> partials summable; segments flushed via f32 atomics.
__global__ __launch_bounds__(256) void diff_attn_persist(
    const unsigned short* __restrict__ q, const unsigned short* __restrict__ kk_,
    const unsigned short* __restrict__ vvt,
    float* __restrict__ accG, float* __restrict__ lsumG) {
    const int p = blockIdx.x;
    int g = (p * TILES_TOTAL) / NBLOCKS;
    const int g1 = ((p + 1) * TILES_TOTAL) / NBLOCKS;

    const int tid = threadIdx.x;
    const int l = tid & 63, wid = tid >> 6;
    const int gq = l >> 4, i16 = l & 15;
    const int branch = wid >> 1, rhalf = wid & 1;
    const float NEGINF = -__builtin_inff();

    __shared__ unsigned short ks[64][136];
    __shared__ unsigned short vt[128][72];
    __shared__ unsigned short ps[4][32][72];

    const int str = tid >> 4;
    const int stc = (tid & 15) * 8;
    const int vrow = tid >> 3;
    const int vcol = (tid & 7) * 8;

    const f32x4 z4 = {0.f, 0.f, 0.f, 0.f};
    uint4 kr0, kr1, kr2, kr3, vr0, vr1, vr2, vr3;

    while (g < g1) {
        const int b = g / 2080;
        const int r_ = g - b * 2080;
        int t = (int)((__builtin_sqrtf((float)(8 * r_ + 1)) - 1.0f) * 0.5f);
        while ((t + 1) * (t + 2) / 2 <= r_) ++t;
        while (t * (t + 1) / 2 > r_) --t;
        const int s0 = r_ - t * (t + 1) / 2;
        const int smax = min(t + 1, s0 + (g1 - g));

        const size_t bbase = (size_t)b * 4096;
        const size_t vbase = (size_t)b * 524288;
        const int qrow0 = t * 64 + rhalf * 32;

        bf16x8 qf[2][2];
        for (int qb = 0; qb < 2; ++qb)
            for (int cc = 0; cc < 2; ++cc)
                qf[qb][cc] = *(const bf16x8*)&q[(bbase + qrow0 + qb * 16 + i16) * 128 + branch * 64 + cc * 32 + 8 * gq];

        float lsum[2] = {0.f, 0.f};
        f32x4 acc_o[2][8];
        for (int rb = 0; rb < 2; ++rb)
            for (int nb = 0; nb < 8; ++nb) acc_o[rb][nb] = z4;

#define KV_LOAD(s_) do {                                                        \
        const unsigned short* kp = &kk_[(bbase + (size_t)(s_) * 64) * 128];     \
        kr0 = *(const uint4*)&kp[(str +  0) * 128 + stc];                       \
        kr1 = *(const uint4*)&kp[(str + 16) * 128 + stc];                       \
        kr2 = *(const uint4*)&kp[(str + 32) * 128 + stc];                       \
        kr3 = *(const uint4*)&kp[(str + 48) * 128 + stc];                       \
        const unsigned short* vp = &vvt[vbase + (size_t)(s_) * 64 + vcol];      \
        vr0 = *(const uint4*)&vp[(size_t)(vrow +  0) * 4096];                   \
        vr1 = *(const uint4*)&vp[(size_t)(vrow + 32) * 4096];                   \
        vr2 = *(const uint4*)&vp[(size_t)(vrow + 64) * 4096];                   \
        vr3 = *(const uint4*)&vp[(size_t)(vrow + 96) * 4096];                   \
    } while (0)

#define KV_STORE() do {                                                         \
        *(uint4*)&ks[str +  0][stc] = kr0;                                      \
        *(uint4*)&ks[str + 16][stc] = kr1;                                      \
        *(uint4*)&ks[str + 32][stc] = kr2;                                      \
        *(uint4*)&ks[str + 48][stc] = kr3;                                      \
        *(uint4*)&vt[vrow +  0][vcol] = vr0;                                    \
        *(uint4*)&vt[vrow + 32][vcol] = vr1;                                    \
        *(uint4*)&vt[vrow + 64][vcol] = vr2;                                    \
        *(uint4*)&vt[vrow + 96][vcol] = vr3;                                    \
    } while (0)

        KV_LOAD(s0);
        for (int s = s0; s < smax; ++s) {
            __syncthreads();
            KV_STORE();
            if (s + 1 < smax) KV_LOAD(s + 1);
            __syncthreads();

            // S^T = mfma(K, Q): sc[qb][cb]; lane: col=i16 -> q-row, rows -> kv
            f32x4 sc[2][4];
            for (int qb = 0; qb < 2; ++qb)
                for (int cb = 0; cb < 4; ++cb) sc[qb][cb] = z4;
            __builtin_amdgcn_s_setprio(1);
            for (int cb = 0; cb < 4; ++cb)
                for (int cc = 0; cc < 2; ++cc) {
                    bf16x8 kf = *(const bf16x8*)&ks[cb * 16 + i16][branch * 64 + cc * 32 + 8 * gq];
                    for (int qb = 0; qb < 2; ++qb)
                        sc[qb][cb] = __builtin_amdgcn_mfma_f32_16x16x32_bf16(kf, qf[qb][cc], sc[qb][cb], 0, 0, 0);
                }
            __builtin_amdgcn_s_setprio(0);
            if (s == t) {  // causal mask: kv_local > q_local
                for (int qb = 0; qb < 2; ++qb) {
                    int ql = rhalf * 32 + qb * 16 + i16;
                    for (int cb = 0; cb < 4; ++cb)
                        for (int r = 0; r < 4; ++r)
                            if (cb * 16 + gq * 4 + r > ql) sc[qb][cb][r] = NEGINF;
                }
            }
            // p = exp2(s*CEXP - MOFF); per-lane lsum (one q-row per lane per qb)
            #pragma unroll
            for (int qb = 0; qb < 2; ++qb)
                for (int cb = 0; cb < 4; ++cb)
                    for (int r = 0; r < 4; ++r) {
                        float pv = exp2f(fmaf(sc[qb][cb][r], CEXP, -MOFF));
                        sc[qb][cb][r] = pv;
                        lsum[qb] += pv;
                    }
            // pack pairs -> b64 writes: ps[wid][q][kv], kv 4-consec per lane
            #pragma unroll
            for (int qb = 0; qb < 2; ++qb)
                for (int cb = 0; cb < 4; ++cb) {
                    uint2 w;
                    w.x = cvt_pk_bf16(sc[qb][cb][0], sc[qb][cb][1]);
                    w.y = cvt_pk_bf16(sc[qb][cb][2], sc[qb][cb][3]);
                    *(uint2*)&ps[wid][qb * 16 + i16][cb * 16 + gq * 4] = w;
                }
            asm volatile("s_waitcnt lgkmcnt(0)" ::: "memory");  // wave-local
            bf16x8 pa[2][2];
            for (int rb = 0; rb < 2; ++rb)
                for (int cc = 0; cc < 2; ++cc)
                    pa[rb][cc] = *(const bf16x8*)&ps[wid][rb * 16 + i16][cc * 32 + 8 * gq];
            __builtin_amdgcn_s_setprio(1);
            for (int nb = 0; nb < 8; ++nb)
                for (int cc = 0; cc < 2; ++cc) {
                    bf16x8 vb = *(const bf16x8*)&vt[nb * 16 + i16][cc * 32 + 8 * gq];
                    for (int rb = 0; rb < 2; ++rb)
                        acc_o[rb][nb] = __builtin_amdgcn_mfma_f32_16x16x32_bf16(pa[rb][cc], vb, acc_o[rb][nb], 0, 0, 0);
                }
            __builtin_amdgcn_s_setprio(0);
        }
#undef KV_LOAD
#undef KV_STORE

        // flush segment: lsum reduce across the 4 gq lane-groups, then atomics
        #pragma unroll
        for (int qb = 0; qb < 2; ++qb) {
            lsum[qb] += __shfl_xor(lsum[qb], 16);
            lsum[qb] += __shfl_xor(lsum[qb], 32);
        }
        {
            float* lb = lsumG + (((size_t)b * 64 + t) * 2 + branch) * 64;
            if (gq == 0)
                for (int qb = 0; qb < 2; ++qb)
                    unsafeAtomicAdd(&lb[rhalf * 32 + qb * 16 + i16], lsum[qb]);
            float* ab = accG + (((size_t)b * 64 + t) * 2 + branch) * 8192;
            for (int rb = 0; rb < 2; ++rb)
                for (int nb = 0; nb < 8; ++nb)
                    for (int r = 0; r < 4; ++r) {
                        int row = rhalf * 32 + rb * 16 + gq * 4 + r;
                        unsafeAtomicAdd(&ab[row * 128 + nb * 16 + i16], acc_o[rb][nb][r]);
                    }
        }
        g += (smax - s0);
    }
}

// ---------------- combine: normalize, o1 - lam*o2 ----------------
__global__ __launch_bounds__(256) void diff_combine(
    const float* __restrict__ accG, const float* __restrict__ lsumG,
    const float* __restrict__ lq1, const float* __restrict__ lq2,
    const float* __restrict__ lk1, const float* __restrict__ lk2,
    float* __restrict__ out) {
    const int t = blockIdx.x, b = blockIdx.y;
    const int tid = threadIdx.x;
    __shared__ float sl[2][64];
    __shared__ float s_lam;

    if (tid < 64) {
        float s1 = lq1[tid] * lk1[tid];
        float s2 = lq2[tid] * lk2[tid];
        for (int off = 32; off > 0; off >>= 1) {
            s1 += __shfl_xor(s1, off);
            s2 += __shfl_xor(s2, off);
        }
        if (tid == 0) s_lam = expf(s1) - expf(s2) + LAMBDA_INIT;
    }
    if (tid < 128) {
        int r = tid & 63, br = tid >> 6;
        sl[br][r] = lsumG[(((size_t)b * 64 + t) * 2 + br) * 64 + r];
    }
    __syncthreads();
    const float lam = s_lam;
    const float* a1 = accG + (((size_t)b * 64 + t) * 2 + 0) * 8192;
    const float* a2 = accG + (((size_t)b * 64 + t) * 2 + 1) * 8192;
    float* op = out + ((size_t)b * 4096 + (size_t)t * 64) * 128;
    #pragma unroll
    for (int it = 0; it < 8; ++it) {
        int e = (it * 256 + tid) * 4;
        int row = e >> 7;
        float4 v1 = *(const float4*)&a1[e];
        float4 v2 = *(const float4*)&a2[e];
        float w1 = 1.0f / sl[0][row];
        float w2 = lam / sl[1][row];
        float4 res;
        res.x = v1.x * w1 - v2.x * w2;
        res.y = v1.y * w1 - v2.y * w2;
        res.z = v1.z * w1 - v2.z * w2;
        res.w = v1.w * w1 - v2.w * w2;
        *(float4*)&op[e] = res;
    }
}

extern "C" void kernel_launch(void* const* d_in, const int* in_sizes, int n_in,
                              void* d_out, int out_size, void* d_ws, size_t ws_size,
                              hipStream_t stream) {
    const float* x   = (const float*)d_in[0];
    const float* Wq  = (const float*)d_in[1];
    const float* Wk  = (const float*)d_in[2];
    const float* Wv  = (const float*)d_in[3];
    const float* lq1 = (const float*)d_in[4];
    const float* lq2 = (const float*)d_in[5];
    const float* lk1 = (const float*)d_in[6];
    const float* lk2 = (const float*)d_in[7];
    float* out = (float*)d_out;
    unsigned short* qkv = (unsigned short*)d_ws;
    float* accG = (float*)((char*)d_ws + ACC_OFF_BYTES);
    float* lsumG = (float*)((char*)d_ws + LSUM_OFF_BYTES);
    unsigned short* WT = (unsigned short*)((char*)d_ws + WT_OFF_BYTES);

    prep_wt<<<dim3(16, 2, 3), 256, 0, stream>>>(Wq, Wk, Wv, WT);
    qkv_gemm<<<dim3(128, 3), 256, 0, stream>>>(x, WT, qkv);
    hipMemsetAsync((char*)d_ws + ACC_OFF_BYTES, 0, (size_t)16777216 + 131072, stream);

    const unsigned short* qb = qkv;
    const unsigned short* kb = qkv + K_OFF;
    const unsigned short* vtb = qkv + VT_OFF;
    diff_attn_persist<<<NBLOCKS, 256, 0, stream>>>(qb, kb, vtb, accG, lsumG);
    diff_combine<<<dim3(64, 4), 256, 0, stream>>>(accG, lsumG, lq1, lq2, lk1, lk2, out);
}

// Round 7
// 125.603 us; speedup vs baseline: 1.1933x; 1.1933x over previous
//
#include <hip/hip_runtime.h>
#include <hip/hip_bf16.h>

typedef __bf16 bf16x8 __attribute__((ext_vector_type(8)));
typedef float f32x4 __attribute__((ext_vector_type(4)));

#define LOG2E 1.4426950408889634f
#define LAMBDA_INIT 0.3555090675909693f
#define CEXP 0.18033688011112042f   // 0.125 * LOG2E
#define MOFF 11.541560327111708f    // 8 * LOG2E  (fixed raw max = 64)

// ws layout (bytes):
//  q   : [0, 4.19M)        bf16 [16384][128]
//  k   : [4.19M, 8.39M)    bf16 [16384][128]
//  vT  : [8.39M, 12.58M)   bf16 [4][128][4096]
//  part: [12.58M, 46.66M)  2048 recs x 16640B  (l[64] f32 + O[64][128] bf16)
//  WT  : [46.66M, 47.45M)  bf16 [3][128][1024]
#define K_OFF   ((size_t)16384 * 128)
#define VT_OFF  ((size_t)2 * 16384 * 128)
#define PART_OFF_BYTES ((size_t)12582912)
#define WT_OFF_BYTES   ((size_t)46661632)
#define REC_FLOATS 4160  // 64 l + 4096 words of bf16 O

__device__ __forceinline__ unsigned short f2bf(float f) {
    __hip_bfloat16 h = __float2bfloat16(f);
    unsigned short u;
    __builtin_memcpy(&u, &h, 2);
    return u;
}
__device__ __forceinline__ float bf2f(unsigned short u) {
    unsigned int x = ((unsigned int)u) << 16;
    float f;
    __builtin_memcpy(&f, &x, 4);
    return f;
}
__device__ __forceinline__ unsigned int cvt_pk_bf16(float a, float b) {
    unsigned int r;
    asm volatile("v_cvt_pk_bf16_f32 %0, %1, %2" : "=v"(r) : "v"(a), "v"(b));
    return r;
}

// ---------------- W pre-transpose: [1024][128] f32 -> [128][1024] bf16 ----------------
__global__ __launch_bounds__(256) void prep_wt(
    const float* __restrict__ Wq, const float* __restrict__ Wk,
    const float* __restrict__ Wv, unsigned short* __restrict__ WT) {
    const int kt = blockIdx.x, nt = blockIdx.y, mat = blockIdx.z;
    const float* W = (mat == 0) ? Wq : (mat == 1) ? Wk : Wv;
    unsigned short* O = WT + (size_t)mat * 128 * 1024;
    __shared__ float tb[64][65];
    const int r = threadIdx.x >> 2, c4 = (threadIdx.x & 3) * 16;
    for (int j = 0; j < 4; ++j) {
        float4 v = *(const float4*)&W[(size_t)(kt * 64 + r) * 128 + nt * 64 + c4 + j * 4];
        tb[r][c4 + j * 4 + 0] = v.x;
        tb[r][c4 + j * 4 + 1] = v.y;
        tb[r][c4 + j * 4 + 2] = v.z;
        tb[r][c4 + j * 4 + 3] = v.w;
    }
    __syncthreads();
    unsigned short tmp[16];
    for (int j = 0; j < 16; ++j) tmp[j] = f2bf(tb[c4 + j][r]);
    *(uint4*)&O[(size_t)(nt * 64 + r) * 1024 + kt * 64 + c4] = *(uint4*)&tmp[0];
    *(uint4*)&O[(size_t)(nt * 64 + r) * 1024 + kt * 64 + c4 + 8] = *(uint4*)&tmp[8];
}

// ---------------- QKV projection ----------------
__global__ __launch_bounds__(256) void qkv_gemm(
    const float* __restrict__ x, const unsigned short* __restrict__ WT,
    unsigned short* __restrict__ qkv) {
    const int tid = threadIdx.x;
    const int l = tid & 63, wid = tid >> 6;
    const int g = l >> 4, i16 = l & 15;
    const int row0 = blockIdx.x * 128;
    const int mat = blockIdx.y;
    const unsigned short* Wt = WT + (size_t)mat * 128 * 1024;

    __shared__ unsigned short smem[2][128][72];
    auto xs = smem[0];
    auto wt = smem[1];

    f32x4 acc[2][8];
    const f32x4 z4 = {0.f, 0.f, 0.f, 0.f};
    for (int a = 0; a < 2; ++a)
        for (int b = 0; b < 8; ++b) acc[a][b] = z4;

    for (int k0 = 0; k0 < 1024; k0 += 64) {
        __syncthreads();
        {
            const int c = (tid & 15) * 4;
            const int rbase = tid >> 4;
            #pragma unroll
            for (int it = 0; it < 8; ++it) {
                int r = rbase + it * 16;
                const float4 v = *(const float4*)&x[(size_t)(row0 + r) * 1024 + k0 + c];
                ushort4 pk = make_ushort4(f2bf(v.x), f2bf(v.y), f2bf(v.z), f2bf(v.w));
                *(ushort4*)&xs[r][c] = pk;
            }
        }
        {
            #pragma unroll
            for (int it = 0; it < 4; ++it) {
                int lin = it * 256 + tid;
                int n = lin >> 3, k8 = (lin & 7) * 8;
                *(uint4*)&wt[n][k8] = *(const uint4*)&Wt[(size_t)n * 1024 + k0 + k8];
            }
        }
        __syncthreads();

        bf16x8 af[2][2];
        for (int rb = 0; rb < 2; ++rb)
            for (int c = 0; c < 2; ++c)
                af[rb][c] = *(const bf16x8*)&xs[wid * 32 + rb * 16 + i16][c * 32 + 8 * g];
        for (int nb = 0; nb < 8; ++nb) {
            bf16x8 b0 = *(const bf16x8*)&wt[nb * 16 + i16][8 * g];
            bf16x8 b1 = *(const bf16x8*)&wt[nb * 16 + i16][32 + 8 * g];
            for (int rb = 0; rb < 2; ++rb) {
                acc[rb][nb] = __builtin_amdgcn_mfma_f32_16x16x32_bf16(af[rb][0], b0, acc[rb][nb], 0, 0, 0);
                acc[rb][nb] = __builtin_amdgcn_mfma_f32_16x16x32_bf16(af[rb][1], b1, acc[rb][nb], 0, 0, 0);
            }
        }
    }

    __syncthreads();
    unsigned short(*ts)[136] = (unsigned short(*)[136]) & smem[0][0][0];
    for (int rb = 0; rb < 2; ++rb)
        for (int nb = 0; nb < 8; ++nb)
            for (int r = 0; r < 4; ++r)
                ts[wid * 32 + rb * 16 + g * 4 + r][nb * 16 + i16] = f2bf(acc[rb][nb][r]);
    __syncthreads();
    if (mat < 2) {
        unsigned short* outp = qkv + (size_t)mat * 16384 * 128 + (size_t)row0 * 128;
        #pragma unroll
        for (int it = 0; it < 8; ++it) {
            int tr = it * 16 + (tid >> 4), dv0 = (tid & 15) * 8;
            *(uint4*)&outp[tr * 128 + dv0] = *(const uint4*)&ts[tr][dv0];
        }
    } else {
        unsigned short* vtb = qkv + VT_OFF + (size_t)(row0 >> 12) * 128 * 4096 + (size_t)(row0 & 4095);
        const int dv = tid >> 1, half = tid & 1;
        #pragma unroll
        for (int blk = 0; blk < 8; ++blk) {
            unsigned short tmp[8];
            #pragma unroll
            for (int j = 0; j < 8; ++j) tmp[j] = ts[half * 64 + blk * 8 + j][dv];
            *(uint4*)&vtb[(size_t)dv * 4096 + half * 64 + blk * 8] = *(uint4*)tmp;
        }
    }
}

// ---------------- Differential causal flash attention ----------------
// grid (32, 4, 4) = 512 uniform blocks, all co-resident (zero scheduling skew).
// Block (bx,b,c) processes chunk c of row t=bx, then chunk c of row t=63-bx:
// total kv-tiles = ~(bx+1)/4 + ~(64-bx)/4 ~= 16.25, near-constant.
// Fixed softmax max (raw 64): no online max, no per-tile cross-lane reductions.
// Swapped QK^T (mfma(K,Q)) so each lane holds 4 consecutive-kv P values ->
// packed v_cvt_pk_bf16_f32 + b64 LDS writes.
__global__ __launch_bounds__(256) void diff_attn_pair(
    const unsigned short* __restrict__ q, const unsigned short* __restrict__ kk_,
    const unsigned short* __restrict__ vvt,
    float* __restrict__ part) {
    const int bx = blockIdx.x, b = blockIdx.y, c = blockIdx.z;

    const int tid = threadIdx.x;
    const int l = tid & 63, wid = tid >> 6;
    const int gq = l >> 4, i16 = l & 15;
    const int branch = wid >> 1, rhalf = wid & 1;
    const float NEGINF = -__builtin_inff();

    __shared__ unsigned short ks[64][136];
    __shared__ unsigned short vt[128][72];
    __shared__ unsigned short ps[4][32][72];

    const int str = tid >> 4;
    const int stc = (tid & 15) * 8;
    const int vrow = tid >> 3;
    const int vcol = (tid & 7) * 8;

    const size_t bbase = (size_t)b * 4096;
    const size_t vbase = (size_t)b * 524288;
    const f32x4 z4 = {0.f, 0.f, 0.f, 0.f};
    uint4 kr0, kr1, kr2, kr3, vr0, vr1, vr2, vr3;

#define KV_LOAD(s_) do {                                                        \
        const unsigned short* kp = &kk_[(bbase + (size_t)(s_) * 64) * 128];     \
        kr0 = *(const uint4*)&kp[(str +  0) * 128 + stc];                       \
        kr1 = *(const uint4*)&kp[(str + 16) * 128 + stc];                       \
        kr2 = *(const uint4*)&kp[(str + 32) * 128 + stc];                       \
        kr3 = *(const uint4*)&kp[(str + 48) * 128 + stc];                       \
        const unsigned short* vp = &vvt[vbase + (size_t)(s_) * 64 + vcol];      \
        vr0 = *(const uint4*)&vp[(size_t)(vrow +  0) * 4096];                   \
        vr1 = *(const uint4*)&vp[(size_t)(vrow + 32) * 4096];                   \
        vr2 = *(const uint4*)&vp[(size_t)(vrow + 64) * 4096];                   \
        vr3 = *(const uint4*)&vp[(size_t)(vrow + 96) * 4096];                   \
    } while (0)

#define KV_STORE() do {                                                         \
        *(uint4*)&ks[str +  0][stc] = kr0;                                      \
        *(uint4*)&ks[str + 16][stc] = kr1;                                      \
        *(uint4*)&ks[str + 32][stc] = kr2;                                      \
        *(uint4*)&ks[str + 48][stc] = kr3;                                      \
        *(uint4*)&vt[vrow +  0][vcol] = vr0;                                    \
        *(uint4*)&vt[vrow + 32][vcol] = vr1;                                    \
        *(uint4*)&vt[vrow + 64][vcol] = vr2;                                    \
        *(uint4*)&vt[vrow + 96][vcol] = vr3;                                    \
    } while (0)

    #pragma unroll 1
    for (int seg = 0; seg < 2; ++seg) {
        const int t = seg ? (63 - bx) : bx;
        const int n = t + 1;
        const int s0 = (c * n) >> 2, smax = ((c + 1) * n) >> 2;

        float* recpair = part + (((size_t)b * 64 + t) * 4 + c) * 2 * REC_FLOATS;
        if (s0 >= smax) {  // empty chunk: zero both branch records
            unsigned int* pz = (unsigned int*)recpair;
            for (int i = tid; i < 2 * REC_FLOATS; i += 256) pz[i] = 0u;
            continue;
        }

        const int qrow0 = t * 64 + rhalf * 32;
        bf16x8 qf[2][2];
        for (int qb = 0; qb < 2; ++qb)
            for (int cc = 0; cc < 2; ++cc)
                qf[qb][cc] = *(const bf16x8*)&q[(bbase + qrow0 + qb * 16 + i16) * 128 + branch * 64 + cc * 32 + 8 * gq];

        float lsum[2] = {0.f, 0.f};
        f32x4 acc_o[2][8];
        for (int rb = 0; rb < 2; ++rb)
            for (int nb = 0; nb < 8; ++nb) acc_o[rb][nb] = z4;

        KV_LOAD(s0);
        #pragma unroll 1
        for (int s = s0; s < smax; ++s) {
            __syncthreads();
            KV_STORE();
            if (s + 1 < smax) KV_LOAD(s + 1);
            __syncthreads();

            // S^T = mfma(K, Q): lane col=i16 -> q-row, rows -> kv
            f32x4 sc[2][4];
            for (int qb = 0; qb < 2; ++qb)
                for (int cb = 0; cb < 4; ++cb) sc[qb][cb] = z4;
            __builtin_amdgcn_s_setprio(1);
            for (int cb = 0; cb < 4; ++cb)
                for (int cc = 0; cc < 2; ++cc) {
                    bf16x8 kf = *(const bf16x8*)&ks[cb * 16 + i16][branch * 64 + cc * 32 + 8 * gq];
                    for (int qb = 0; qb < 2; ++qb)
                        sc[qb][cb] = __builtin_amdgcn_mfma_f32_16x16x32_bf16(kf, qf[qb][cc], sc[qb][cb], 0, 0, 0);
                }
            __builtin_amdgcn_s_setprio(0);
            if (s == t) {  // causal mask on diagonal tile
                for (int qb = 0; qb < 2; ++qb) {
                    int ql = rhalf * 32 + qb * 16 + i16;
                    for (int cb = 0; cb < 4; ++cb)
                        for (int r = 0; r < 4; ++r)
                            if (cb * 16 + gq * 4 + r > ql) sc[qb][cb][r] = NEGINF;
                }
            }
            // p = exp2(s*CEXP - MOFF); fixed max, per-lane lsum
            #pragma unroll
            for (int qb = 0; qb < 2; ++qb)
                for (int cb = 0; cb < 4; ++cb)
                    for (int r = 0; r < 4; ++r) {
                        float pv = exp2f(fmaf(sc[qb][cb][r], CEXP, -MOFF));
                        sc[qb][cb][r] = pv;
                        lsum[qb] += pv;
                    }
            // pack pairs -> b64 LDS writes: ps[wid][q][kv]
            #pragma unroll
            for (int qb = 0; qb < 2; ++qb)
                for (int cb = 0; cb < 4; ++cb) {
                    uint2 w;
                    w.x = cvt_pk_bf16(sc[qb][cb][0], sc[qb][cb][1]);
                    w.y = cvt_pk_bf16(sc[qb][cb][2], sc[qb][cb][3]);
                    *(uint2*)&ps[wid][qb * 16 + i16][cb * 16 + gq * 4] = w;
                }
            asm volatile("s_waitcnt lgkmcnt(0)" ::: "memory");  // wave-local
            bf16x8 pa[2][2];
            for (int rb = 0; rb < 2; ++rb)
                for (int cc = 0; cc < 2; ++cc)
                    pa[rb][cc] = *(const bf16x8*)&ps[wid][rb * 16 + i16][cc * 32 + 8 * gq];
            __builtin_amdgcn_s_setprio(1);
            for (int nb = 0; nb < 8; ++nb)
                for (int cc = 0; cc < 2; ++cc) {
                    bf16x8 vb = *(const bf16x8*)&vt[nb * 16 + i16][cc * 32 + 8 * gq];
                    for (int rb = 0; rb < 2; ++rb)
                        acc_o[rb][nb] = __builtin_amdgcn_mfma_f32_16x16x32_bf16(pa[rb][cc], vb, acc_o[rb][nb], 0, 0, 0);
                }
            __builtin_amdgcn_s_setprio(0);
        }

        // flush: reduce lsum across the 4 gq lane-groups, direct stores
        #pragma unroll
        for (int qb = 0; qb < 2; ++qb) {
            lsum[qb] += __shfl_xor(lsum[qb], 16);
            lsum[qb] += __shfl_xor(lsum[qb], 32);
        }
        float* rec = recpair + (size_t)branch * REC_FLOATS;
        unsigned short* Orec = (unsigned short*)(rec + 64);
        if (gq == 0)
            for (int qb = 0; qb < 2; ++qb)
                rec[rhalf * 32 + qb * 16 + i16] = lsum[qb];
        for (int rb = 0; rb < 2; ++rb)
            for (int nb = 0; nb < 8; ++nb)
                for (int r = 0; r < 4; ++r) {
                    int row = rhalf * 32 + rb * 16 + gq * 4 + r;
                    Orec[row * 128 + nb * 16 + i16] = f2bf(acc_o[rb][nb][r]);
                }
    }
#undef KV_LOAD
#undef KV_STORE
}

// ---------------- combine: sum 4 chunks per branch, normalize, o1 - lam*o2 ----------------
__global__ __launch_bounds__(256) void diff_combine(
    const float* __restrict__ part,
    const float* __restrict__ lq1, const float* __restrict__ lq2,
    const float* __restrict__ lk1, const float* __restrict__ lk2,
    float* __restrict__ out) {
    const int t = blockIdx.x, b = blockIdx.y;
    const int tid = threadIdx.x;
    __shared__ float sl[2][64];
    __shared__ float s_lam;

    const float* recbase = part + (((size_t)b * 64 + t) * 4) * 2 * REC_FLOATS;

    if (tid < 64) {
        float s1 = lq1[tid] * lk1[tid];
        float s2 = lq2[tid] * lk2[tid];
        for (int off = 32; off > 0; off >>= 1) {
            s1 += __shfl_xor(s1, off);
            s2 += __shfl_xor(s2, off);
        }
        if (tid == 0) s_lam = expf(s1) - expf(s2) + LAMBDA_INIT;
    }
    if (tid < 128) {
        int r = tid & 63, br = tid >> 6;
        float acc = 0.f;
        for (int c = 0; c < 4; ++c) acc += recbase[(c * 2 + br) * REC_FLOATS + r];
        sl[br][r] = acc;
    }
    __syncthreads();
    const float lam = s_lam;

    float* op = out + ((size_t)b * 4096 + (size_t)t * 64) * 128;
    for (int grp = 0; grp < 4; ++grp) {
        int gid = grp * 256 + tid;
        int e = gid * 8;
        int row = e >> 7;
        float o1[8] = {0, 0, 0, 0, 0, 0, 0, 0}, o2[8] = {0, 0, 0, 0, 0, 0, 0, 0};
        #pragma unroll
        for (int c = 0; c < 4; ++c) {
            const unsigned short* O0 = (const unsigned short*)(recbase + (c * 2 + 0) * REC_FLOATS + 64);
            const unsigned short* O1 = (const unsigned short*)(recbase + (c * 2 + 1) * REC_FLOATS + 64);
            uint4 u0 = *(const uint4*)&O0[e];
            uint4 u1 = *(const uint4*)&O1[e];
            const unsigned short* e0 = (const unsigned short*)&u0;
            const unsigned short* e1 = (const unsigned short*)&u1;
            #pragma unroll
            for (int j = 0; j < 8; ++j) {
                o1[j] += bf2f(e0[j]);
                o2[j] += bf2f(e1[j]);
            }
        }
        float l1inv = 1.0f / sl[0][row], l2inv = 1.0f / sl[1][row];
        float res[8];
        #pragma unroll
        for (int j = 0; j < 8; ++j) res[j] = o1[j] * l1inv - lam * o2[j] * l2inv;
        *(float4*)&op[e] = *(float4*)&res[0];
        *(float4*)&op[e + 4] = *(float4*)&res[4];
    }
}

extern "C" void kernel_launch(void* const* d_in, const int* in_sizes, int n_in,
                              void* d_out, int out_size, void* d_ws, size_t ws_size,
                              hipStream_t stream) {
    const float* x   = (const float*)d_in[0];
    const float* Wq  = (const float*)d_in[1];
    const float* Wk  = (const float*)d_in[2];
    const float* Wv  = (const float*)d_in[3];
    const float* lq1 = (const float*)d_in[4];
    const float* lq2 = (const float*)d_in[5];
    const float* lk1 = (const float*)d_in[6];
    const float* lk2 = (const float*)d_in[7];
    float* out = (float*)d_out;
    unsigned short* qkv = (unsigned short*)d_ws;
    float* part = (float*)((char*)d_ws + PART_OFF_BYTES);
    unsigned short* WT = (unsigned short*)((char*)d_ws + WT_OFF_BYTES);

    prep_wt<<<dim3(16, 2, 3), 256, 0, stream>>>(Wq, Wk, Wv, WT);
    qkv_gemm<<<dim3(128, 3), 256, 0, stream>>>(x, WT, qkv);

    const unsigned short* qb = qkv;
    const unsigned short* kb = qkv + K_OFF;
    const unsigned short* vtb = qkv + VT_OFF;
    diff_attn_pair<<<dim3(32, 4, 4), 256, 0, stream>>>(qb, kb, vtb, part);
    diff_combine<<<dim3(64, 4), 256, 0, stream>>>(part, lq1, lq2, lk1, lk2, out);
}

// Round 8
// 104.949 us; speedup vs baseline: 1.4282x; 1.1968x over previous
//
#include <hip/hip_runtime.h>
#include <hip/hip_bf16.h>

typedef __bf16 bf16x8 __attribute__((ext_vector_type(8)));
typedef float f32x4 __attribute__((ext_vector_type(4)));

#define LOG2E 1.4426950408889634f
#define LAMBDA_INIT 0.3555090675909693f
#define CEXP 0.18033688011112042f   // 0.125 * LOG2E
#define MOFF 11.541560327111708f    // 8 * LOG2E  (fixed raw max = 64)

// ws layout (bytes):
//  q   : [0, 4.19M)        bf16 [16384][128]
//  k   : [4.19M, 8.39M)    bf16 [16384][128]
//  vT  : [8.39M, 12.58M)   bf16 [4][128][4096]
//  part: [12.58M, 46.66M)  2048 recs x 16640B  (l[64] f32 + O[64][128] bf16)
//  WT  : [46.66M, 47.45M)  bf16 [3][128][1024]
#define K_OFF   ((size_t)16384 * 128)
#define VT_OFF  ((size_t)2 * 16384 * 128)
#define PART_OFF_BYTES ((size_t)12582912)
#define WT_OFF_BYTES   ((size_t)46661632)
#define REC_FLOATS 4160  // 64 l + 4096 words of bf16 O

__device__ __forceinline__ unsigned short f2bf(float f) {
    __hip_bfloat16 h = __float2bfloat16(f);
    unsigned short u;
    __builtin_memcpy(&u, &h, 2);
    return u;
}
__device__ __forceinline__ float bf2f(unsigned short u) {
    unsigned int x = ((unsigned int)u) << 16;
    float f;
    __builtin_memcpy(&f, &x, 4);
    return f;
}
__device__ __forceinline__ unsigned int cvt_pk_bf16(float a, float b) {
    unsigned int r;
    asm volatile("v_cvt_pk_bf16_f32 %0, %1, %2" : "=v"(r) : "v"(a), "v"(b));
    return r;
}

// ---------------- W pre-transpose: [1024][128] f32 -> [128][1024] bf16 ----------------
__global__ __launch_bounds__(256) void prep_wt(
    const float* __restrict__ Wq, const float* __restrict__ Wk,
    const float* __restrict__ Wv, unsigned short* __restrict__ WT) {
    const int kt = blockIdx.x, nt = blockIdx.y, mat = blockIdx.z;
    const float* W = (mat == 0) ? Wq : (mat == 1) ? Wk : Wv;
    unsigned short* O = WT + (size_t)mat * 128 * 1024;
    __shared__ float tb[64][65];
    const int r = threadIdx.x >> 2, c4 = (threadIdx.x & 3) * 16;
    for (int j = 0; j < 4; ++j) {
        float4 v = *(const float4*)&W[(size_t)(kt * 64 + r) * 128 + nt * 64 + c4 + j * 4];
        tb[r][c4 + j * 4 + 0] = v.x;
        tb[r][c4 + j * 4 + 1] = v.y;
        tb[r][c4 + j * 4 + 2] = v.z;
        tb[r][c4 + j * 4 + 3] = v.w;
    }
    __syncthreads();
    unsigned short tmp[16];
    for (int j = 0; j < 16; ++j) tmp[j] = f2bf(tb[c4 + j][r]);
    *(uint4*)&O[(size_t)(nt * 64 + r) * 1024 + kt * 64 + c4] = *(uint4*)&tmp[0];
    *(uint4*)&O[(size_t)(nt * 64 + r) * 1024 + kt * 64 + c4 + 8] = *(uint4*)&tmp[8];
}

// ---------------- QKV projection ----------------
__global__ __launch_bounds__(256) void qkv_gemm(
    const float* __restrict__ x, const unsigned short* __restrict__ WT,
    unsigned short* __restrict__ qkv) {
    const int tid = threadIdx.x;
    const int l = tid & 63, wid = tid >> 6;
    const int g = l >> 4, i16 = l & 15;
    const int row0 = blockIdx.x * 128;
    const int mat = blockIdx.y;
    const unsigned short* Wt = WT + (size_t)mat * 128 * 1024;

    __shared__ unsigned short smem[2][128][72];
    auto xs = smem[0];
    auto wt = smem[1];

    f32x4 acc[2][8];
    const f32x4 z4 = {0.f, 0.f, 0.f, 0.f};
    for (int a = 0; a < 2; ++a)
        for (int b = 0; b < 8; ++b) acc[a][b] = z4;

    for (int k0 = 0; k0 < 1024; k0 += 64) {
        __syncthreads();
        {
            const int c = (tid & 15) * 4;
            const int rbase = tid >> 4;
            #pragma unroll
            for (int it = 0; it < 8; ++it) {
                int r = rbase + it * 16;
                const float4 v = *(const float4*)&x[(size_t)(row0 + r) * 1024 + k0 + c];
                ushort4 pk = make_ushort4(f2bf(v.x), f2bf(v.y), f2bf(v.z), f2bf(v.w));
                *(ushort4*)&xs[r][c] = pk;
            }
        }
        {
            #pragma unroll
            for (int it = 0; it < 4; ++it) {
                int lin = it * 256 + tid;
                int n = lin >> 3, k8 = (lin & 7) * 8;
                *(uint4*)&wt[n][k8] = *(const uint4*)&Wt[(size_t)n * 1024 + k0 + k8];
            }
        }
        __syncthreads();

        bf16x8 af[2][2];
        for (int rb = 0; rb < 2; ++rb)
            for (int c = 0; c < 2; ++c)
                af[rb][c] = *(const bf16x8*)&xs[wid * 32 + rb * 16 + i16][c * 32 + 8 * g];
        for (int nb = 0; nb < 8; ++nb) {
            bf16x8 b0 = *(const bf16x8*)&wt[nb * 16 + i16][8 * g];
            bf16x8 b1 = *(const bf16x8*)&wt[nb * 16 + i16][32 + 8 * g];
            for (int rb = 0; rb < 2; ++rb) {
                acc[rb][nb] = __builtin_amdgcn_mfma_f32_16x16x32_bf16(af[rb][0], b0, acc[rb][nb], 0, 0, 0);
                acc[rb][nb] = __builtin_amdgcn_mfma_f32_16x16x32_bf16(af[rb][1], b1, acc[rb][nb], 0, 0, 0);
            }
        }
    }

    __syncthreads();
    unsigned short(*ts)[136] = (unsigned short(*)[136]) & smem[0][0][0];
    for (int rb = 0; rb < 2; ++rb)
        for (int nb = 0; nb < 8; ++nb)
            for (int r = 0; r < 4; ++r)
                ts[wid * 32 + rb * 16 + g * 4 + r][nb * 16 + i16] = f2bf(acc[rb][nb][r]);
    __syncthreads();
    if (mat < 2) {
        unsigned short* outp = qkv + (size_t)mat * 16384 * 128 + (size_t)row0 * 128;
        #pragma unroll
        for (int it = 0; it < 8; ++it) {
            int tr = it * 16 + (tid >> 4), dv0 = (tid & 15) * 8;
            *(uint4*)&outp[tr * 128 + dv0] = *(const uint4*)&ts[tr][dv0];
        }
    } else {
        unsigned short* vtb = qkv + VT_OFF + (size_t)(row0 >> 12) * 128 * 4096 + (size_t)(row0 & 4095);
        const int dv = tid >> 1, half = tid & 1;
        #pragma unroll
        for (int blk = 0; blk < 8; ++blk) {
            unsigned short tmp[8];
            #pragma unroll
            for (int j = 0; j < 8; ++j) tmp[j] = ts[half * 64 + blk * 8 + j][dv];
            *(uint4*)&vtb[(size_t)dv * 4096 + half * 64 + blk * 8] = *(uint4*)tmp;
        }
    }
}

// ---------------- Differential causal flash attention ----------------
// grid (32, 4, 8) = 1024 blocks: z = c*2+branch. Block (bx,b,c,branch) processes
// chunk c of rows t=bx and t=63-bx for ONE branch. 4 waves x 16 q-rows each.
// 36.9 KB LDS -> 4 blocks/CU -> 16 waves/CU resident (vs 8 in round 7).
// Fixed softmax max; swapped QK^T (mfma(K,Q)); packed cvt_pk P-bounce.
__global__ __launch_bounds__(256) void diff_attn_pair(
    const unsigned short* __restrict__ q, const unsigned short* __restrict__ kk_,
    const unsigned short* __restrict__ vvt,
    float* __restrict__ part) {
    const int bx = blockIdx.x, b = blockIdx.y;
    const int c = blockIdx.z >> 1, branch = blockIdx.z & 1;

    const int tid = threadIdx.x;
    const int l = tid & 63, w = tid >> 6;   // wave id 0..3 -> q rows w*16..
    const int gq = l >> 4, i16 = l & 15;
    const float NEGINF = -__builtin_inff();

    __shared__ unsigned short ks[64][72];     // K branch-half [kv][d0..63]
    __shared__ unsigned short vt[128][72];    // V^T [dv][kv]
    __shared__ unsigned short ps[4][16][72];  // per-wave P bounce [q][kv]

    const int krow = tid >> 3;            // K stage row 0..31 (+32)
    const int kcol = (tid & 7) * 8;       // K stage col 0..56
    const int vrow = tid >> 3;            // V stage row 0..31 (+32/64/96)
    const int vcol = (tid & 7) * 8;

    const size_t bbase = (size_t)b * 4096;
    const size_t vbase = (size_t)b * 524288;
    const f32x4 z4 = {0.f, 0.f, 0.f, 0.f};
    uint4 kr0, kr1, vr0, vr1, vr2, vr3;

#define KV_LOAD(s_) do {                                                            \
        const unsigned short* kp = &kk_[(bbase + (size_t)(s_) * 64) * 128 + branch * 64 + kcol]; \
        kr0 = *(const uint4*)&kp[(size_t)(krow +  0) * 128];                        \
        kr1 = *(const uint4*)&kp[(size_t)(krow + 32) * 128];                        \
        const unsigned short* vp = &vvt[vbase + (size_t)(s_) * 64 + vcol];          \
        vr0 = *(const uint4*)&vp[(size_t)(vrow +  0) * 4096];                       \
        vr1 = *(const uint4*)&vp[(size_t)(vrow + 32) * 4096];                       \
        vr2 = *(const uint4*)&vp[(size_t)(vrow + 64) * 4096];                       \
        vr3 = *(const uint4*)&vp[(size_t)(vrow + 96) * 4096];                       \
    } while (0)

#define KV_STORE() do {                                                             \
        *(uint4*)&ks[krow +  0][kcol] = kr0;                                        \
        *(uint4*)&ks[krow + 32][kcol] = kr1;                                        \
        *(uint4*)&vt[vrow +  0][vcol] = vr0;                                        \
        *(uint4*)&vt[vrow + 32][vcol] = vr1;                                        \
        *(uint4*)&vt[vrow + 64][vcol] = vr2;                                        \
        *(uint4*)&vt[vrow + 96][vcol] = vr3;                                        \
    } while (0)

    #pragma unroll 1
    for (int seg = 0; seg < 2; ++seg) {
        const int t = seg ? (63 - bx) : bx;
        const int n = t + 1;
        const int s0 = (c * n) >> 2, smax = ((c + 1) * n) >> 2;

        float* rec = part + ((((size_t)b * 64 + t) * 4 + c) * 2 + branch) * REC_FLOATS;
        if (s0 >= smax) {  // empty chunk: zero this branch's record
            unsigned int* pz = (unsigned int*)rec;
            for (int i = tid; i < REC_FLOATS; i += 256) pz[i] = 0u;
            continue;
        }

        // Q fragments: wave w owns q rows t*64 + w*16 + i16 (B operand, col=i16)
        bf16x8 qf[2];
        for (int cc = 0; cc < 2; ++cc)
            qf[cc] = *(const bf16x8*)&q[(bbase + t * 64 + w * 16 + i16) * 128 + branch * 64 + cc * 32 + 8 * gq];

        float lsum = 0.f;
        f32x4 acc_o[8];
        for (int nb = 0; nb < 8; ++nb) acc_o[nb] = z4;

        KV_LOAD(s0);
        #pragma unroll 1
        for (int s = s0; s < smax; ++s) {
            __syncthreads();
            KV_STORE();
            if (s + 1 < smax) KV_LOAD(s + 1);
            __syncthreads();

            // S^T = mfma(K, Q): sc[cb]; lane holds S[kv=cb*16+gq*4+r][q=w*16+i16]
            f32x4 sc[4];
            for (int cb = 0; cb < 4; ++cb) sc[cb] = z4;
            __builtin_amdgcn_s_setprio(1);
            for (int cb = 0; cb < 4; ++cb)
                for (int cc = 0; cc < 2; ++cc) {
                    bf16x8 kf = *(const bf16x8*)&ks[cb * 16 + i16][cc * 32 + 8 * gq];
                    sc[cb] = __builtin_amdgcn_mfma_f32_16x16x32_bf16(kf, qf[cc], sc[cb], 0, 0, 0);
                }
            __builtin_amdgcn_s_setprio(0);
            if (s == t) {  // causal mask on diagonal tile
                int ql = w * 16 + i16;
                for (int cb = 0; cb < 4; ++cb)
                    for (int r = 0; r < 4; ++r)
                        if (cb * 16 + gq * 4 + r > ql) sc[cb][r] = NEGINF;
            }
            // p = exp2(s*CEXP - MOFF); fixed max, per-lane lsum
            #pragma unroll
            for (int cb = 0; cb < 4; ++cb)
                for (int r = 0; r < 4; ++r) {
                    float pv = exp2f(fmaf(sc[cb][r], CEXP, -MOFF));
                    sc[cb][r] = pv;
                    lsum += pv;
                }
            // pack pairs -> b64 LDS writes: ps[w][q][kv]
            #pragma unroll
            for (int cb = 0; cb < 4; ++cb) {
                uint2 pw;
                pw.x = cvt_pk_bf16(sc[cb][0], sc[cb][1]);
                pw.y = cvt_pk_bf16(sc[cb][2], sc[cb][3]);
                *(uint2*)&ps[w][i16][cb * 16 + gq * 4] = pw;
            }
            asm volatile("s_waitcnt lgkmcnt(0)" ::: "memory");  // wave-local
            bf16x8 pa[2];
            for (int cc = 0; cc < 2; ++cc)
                pa[cc] = *(const bf16x8*)&ps[w][i16][cc * 32 + 8 * gq];
            __builtin_amdgcn_s_setprio(1);
            for (int nb = 0; nb < 8; ++nb)
                for (int cc = 0; cc < 2; ++cc) {
                    bf16x8 vb = *(const bf16x8*)&vt[nb * 16 + i16][cc * 32 + 8 * gq];
                    acc_o[nb] = __builtin_amdgcn_mfma_f32_16x16x32_bf16(pa[cc], vb, acc_o[nb], 0, 0, 0);
                }
            __builtin_amdgcn_s_setprio(0);
        }

        // flush: reduce lsum across the 4 gq lane-groups, direct stores
        lsum += __shfl_xor(lsum, 16);
        lsum += __shfl_xor(lsum, 32);
        unsigned short* Orec = (unsigned short*)(rec + 64);
        if (gq == 0) rec[w * 16 + i16] = lsum;
        for (int nb = 0; nb < 8; ++nb)
            for (int r = 0; r < 4; ++r) {
                int row = w * 16 + gq * 4 + r;  // q row local; PV C row = gq*4+r
                Orec[row * 128 + nb * 16 + i16] = f2bf(acc_o[nb][r]);
            }
    }
#undef KV_LOAD
#undef KV_STORE
}

// ---------------- combine: sum 4 chunks per branch, normalize, o1 - lam*o2 ----------------
__global__ __launch_bounds__(256) void diff_combine(
    const float* __restrict__ part,
    const float* __restrict__ lq1, const float* __restrict__ lq2,
    const float* __restrict__ lk1, const float* __restrict__ lk2,
    float* __restrict__ out) {
    const int t = blockIdx.x, b = blockIdx.y;
    const int tid = threadIdx.x;
    __shared__ float sl[2][64];
    __shared__ float s_lam;

    const float* recbase = part + (((size_t)b * 64 + t) * 4) * 2 * REC_FLOATS;

    if (tid < 64) {
        float s1 = lq1[tid] * lk1[tid];
        float s2 = lq2[tid] * lk2[tid];
        for (int off = 32; off > 0; off >>= 1) {
            s1 += __shfl_xor(s1, off);
            s2 += __shfl_xor(s2, off);
        }
        if (tid == 0) s_lam = expf(s1) - expf(s2) + LAMBDA_INIT;
    }
    if (tid < 128) {
        int r = tid & 63, br = tid >> 6;
        float acc = 0.f;
        for (int c = 0; c < 4; ++c) acc += recbase[(c * 2 + br) * REC_FLOATS + r];
        sl[br][r] = acc;
    }
    __syncthreads();
    const float lam = s_lam;

    float* op = out + ((size_t)b * 4096 + (size_t)t * 64) * 128;
    for (int grp = 0; grp < 4; ++grp) {
        int gid = grp * 256 + tid;
        int e = gid * 8;
        int row = e >> 7;
        float o1[8] = {0, 0, 0, 0, 0, 0, 0, 0}, o2[8] = {0, 0, 0, 0, 0, 0, 0, 0};
        #pragma unroll
        for (int c = 0; c < 4; ++c) {
            const unsigned short* O0 = (const unsigned short*)(recbase + (c * 2 + 0) * REC_FLOATS + 64);
            const unsigned short* O1 = (const unsigned short*)(recbase + (c * 2 + 1) * REC_FLOATS + 64);
            uint4 u0 = *(const uint4*)&O0[e];
            uint4 u1 = *(const uint4*)&O1[e];
            const unsigned short* e0 = (const unsigned short*)&u0;
            const unsigned short* e1 = (const unsigned short*)&u1;
            #pragma unroll
            for (int j = 0; j < 8; ++j) {
                o1[j] += bf2f(e0[j]);
                o2[j] += bf2f(e1[j]);
            }
        }
        float l1inv = 1.0f / sl[0][row], l2inv = 1.0f / sl[1][row];
        float res[8];
        #pragma unroll
        for (int j = 0; j < 8; ++j) res[j] = o1[j] * l1inv - lam * o2[j] * l2inv;
        *(float4*)&op[e] = *(float4*)&res[0];
        *(float4*)&op[e + 4] = *(float4*)&res[4];
    }
}

extern "C" void kernel_launch(void* const* d_in, const int* in_sizes, int n_in,
                              void* d_out, int out_size, void* d_ws, size_t ws_size,
                              hipStream_t stream) {
    const float* x   = (const float*)d_in[0];
    const float* Wq  = (const float*)d_in[1];
    const float* Wk  = (const float*)d_in[2];
    const float* Wv  = (const float*)d_in[3];
    const float* lq1 = (const float*)d_in[4];
    const float* lq2 = (const float*)d_in[5];
    const float* lk1 = (const float*)d_in[6];
    const float* lk2 = (const float*)d_in[7];
    float* out = (float*)d_out;
    unsigned short* qkv = (unsigned short*)d_ws;
    float* part = (float*)((char*)d_ws + PART_OFF_BYTES);
    unsigned short* WT = (unsigned short*)((char*)d_ws + WT_OFF_BYTES);

    prep_wt<<<dim3(16, 2, 3), 256, 0, stream>>>(Wq, Wk, Wv, WT);
    qkv_gemm<<<dim3(128, 3), 256, 0, stream>>>(x, WT, qkv);

    const unsigned short* qb = qkv;
    const unsigned short* kb = qkv + K_OFF;
    const unsigned short* vtb = qkv + VT_OFF;
    diff_attn_pair<<<dim3(32, 4, 8), 256, 0, stream>>>(qb, kb, vtb, part);
    diff_combine<<<dim3(64, 4), 256, 0, stream>>>(part, lq1, lq2, lk1, lk2, out);
}